// Round 12
// baseline (680.204 us; speedup 1.0000x reference)
//
#include <hip/hip_runtime.h>
#include <cstdint>

#define EPS_BN 1e-5f

typedef __attribute__((ext_vector_type(8))) short s16x8;
typedef __attribute__((ext_vector_type(4))) float f32x4;
typedef __attribute__((ext_vector_type(4))) unsigned int u32x4;

__device__ __forceinline__ float bf2f(short s){
  unsigned int u = ((unsigned int)(unsigned short)s) << 16;
  return __builtin_bit_cast(float, u);
}
__device__ __forceinline__ unsigned int cvtpk_bf16(float lo, float hi){
  unsigned int r;
  asm("v_cvt_pk_bf16_f32 %0, %1, %2" : "=v"(r) : "v"(lo), "v"(hi));
  return r;
}
__device__ __forceinline__ short f2bf(float f){
  return (short)(unsigned short)(cvtpk_bf16(f, f) & 0xffffu);
}

// ---------------- P0: fused prep: pack W (blocks 0..287) + feats->bf16 ------
// pack layout: frag[t in 0..18)[n in 0..4)[lane in 0..64)[j in 0..8)
//   cin = (t&1)*32 + (lane>>4)*8 + j, cout = n*16 + (lane&15), tap = t>>1
__global__ __launch_bounds__(256) void prep(const float* __restrict__ in,
                                            short* __restrict__ out, long nvec8,
                                            const float* __restrict__ W1,
                                            const float* __restrict__ W2,
                                            short* __restrict__ W1F,
                                            short* __restrict__ W2F){
  if (blockIdx.x < 288){
    int o = blockIdx.x * 256 + threadIdx.x;
    if (o >= 2*36864) return;
    const float* W = (o < 36864) ? W1 : W2;
    short* D = (o < 36864) ? W1F : W2F;
    int oo = o % 36864;
    int j = oo & 7;
    int l = (oo >> 3) & 63;
    int n = (oo >> 9) & 3;
    int t = oo >> 11;
    int tap = t >> 1, h = t & 1, g = l >> 4;
    int cin = h*32 + g*8 + j;
    int cout = n*16 + (l & 15);
    float v = W[((long)tap*64 + cin)*64 + cout];
    D[oo] = f2bf(v);
    return;
  }
  long t = (long)(blockIdx.x - 288) * blockDim.x + threadIdx.x;
  long stride = (long)(gridDim.x - 288) * blockDim.x;
  for (long v = t; v < nvec8; v += stride){
    const f32x4* p = (const f32x4*)in + 2*v;
    f32x4 a = __builtin_nontemporal_load(p);
    f32x4 b = __builtin_nontemporal_load(p + 1);
    u32x4 w;
    w[0] = cvtpk_bf16(a[0], a[1]); w[1] = cvtpk_bf16(a[2], a[3]);
    w[2] = cvtpk_bf16(b[0], b[1]); w[3] = cvtpk_bf16(b[2], b[3]);
    ((u32x4*)out)[v] = w;   // gather table: keep cached
  }
}

// ---------------- conv: Y[N,64] = sum_k gather(src,nbr[:,k]) @ W[k] ----------
// Round-9 conv + ONE launch-side change: kernel takes a block offset blk0 so
// each conv can be dispatched as two half-N launches (halves the dirty-output
// footprint per launch -> gather table stays L3-resident). Internals verbatim.
// AFFINE: apply relu(x*scale+shift) to gathered bf16 values (conv2 path).
template<bool AFFINE>
__global__ __launch_bounds__(256, 2) void conv_mfma(const short* __restrict__ src,
                                                    const int* __restrict__ nbr,
                                                    const short* __restrict__ wfrag,
                                                    const float* __restrict__ scale,
                                                    const float* __restrict__ shiftv,
                                                    short* __restrict__ ybf,
                                                    float* __restrict__ part,
                                                    int N, int nblk, int blk0){
  __shared__ short ldsW[36864]; // 72 KiB: 18 k-steps * 4 col-tiles * 64 lanes * 8 bf16
  __shared__ float red[4][16][8];
  const int tid = threadIdx.x;
  {
    const s16x8* gs = (const s16x8*)wfrag;
    s16x8* ls = (s16x8*)ldsW;
    #pragma unroll
    for (int i = 0; i < 18; ++i) ls[i*256 + tid] = gs[i*256 + tid];
  }
  const int lane = tid & 63;
  const int wave = tid >> 6;
  const int l15 = lane & 15;
  const int g = lane >> 4;
  const int blk = blockIdx.x + blk0;
  const long rowbase = (long)blk * 256 + wave * 64;

  float sc[2][8], sh[2][8];
  if (AFFINE){
    #pragma unroll
    for (int h = 0; h < 2; ++h)
      #pragma unroll
      for (int j = 0; j < 8; ++j){
        int ch = h*32 + g*8 + j;
        sc[h][j] = scale[ch];
        sh[h][j] = shiftv[ch];
      }
  }

  // hoist ALL neighbor indices (9 taps x 4 row-tiles) before the K loop
  int idx[9][4];
  #pragma unroll
  for (int rt = 0; rt < 4; ++rt){
    long row = rowbase + rt*16 + l15;
    const int* np = nbr + row*9;
    const bool v = (row < N);
    #pragma unroll
    for (int t9 = 0; t9 < 9; ++t9)
      idx[t9][rt] = v ? np[t9] : 0;
  }

  f32x4 acc[4][4];
  #pragma unroll
  for (int rt = 0; rt < 4; ++rt)
    #pragma unroll
    for (int n = 0; n < 4; ++n)
      acc[rt][n] = (f32x4){0.f, 0.f, 0.f, 0.f};

  __syncthreads();

  // depth-1 software pipeline: ping-pong buffers, fully unrolled tap loop
  s16x8 avp[2][4][2];
  #pragma unroll
  for (int rt = 0; rt < 4; ++rt){
    const short* p = src + (long)idx[0][rt]*64 + g*8;
    avp[0][rt][0] = *(const s16x8*)(p);
    avp[0][rt][1] = *(const s16x8*)(p + 32);
  }

  #pragma unroll
  for (int tap = 0; tap < 9; ++tap){
    const int cur = tap & 1, nxt = cur ^ 1;
    if (tap < 8){
      #pragma unroll
      for (int rt = 0; rt < 4; ++rt){
        const short* p = src + (long)idx[tap+1][rt]*64 + g*8;
        avp[nxt][rt][0] = *(const s16x8*)(p);
        avp[nxt][rt][1] = *(const s16x8*)(p + 32);
      }
    }
    s16x8 av[4][2];
    #pragma unroll
    for (int rt = 0; rt < 4; ++rt){
      av[rt][0] = avp[cur][rt][0];
      av[rt][1] = avp[cur][rt][1];
    }
    if (AFFINE){
      #pragma unroll
      for (int rt = 0; rt < 4; ++rt)
        #pragma unroll
        for (int h = 0; h < 2; ++h){
          u32x4 w = __builtin_bit_cast(u32x4, av[rt][h]);
          #pragma unroll
          for (int jw = 0; jw < 4; ++jw){
            float f0 = __builtin_bit_cast(float, w[jw] << 16);
            float f1 = __builtin_bit_cast(float, w[jw] & 0xffff0000u);
            f0 = fmaxf(fmaf(f0, sc[h][2*jw],   sh[h][2*jw]),   0.f);
            f1 = fmaxf(fmaf(f1, sc[h][2*jw+1], sh[h][2*jw+1]), 0.f);
            w[jw] = cvtpk_bf16(f0, f1);
          }
          av[rt][h] = __builtin_bit_cast(s16x8, w);
        }
    }
    #pragma unroll
    for (int h = 0; h < 2; ++h){
      const int t = tap*2 + h;
      s16x8 bv[4];
      #pragma unroll
      for (int n = 0; n < 4; ++n)
        bv[n] = *(const s16x8*)&ldsW[((t*4 + n)*64 + lane)*8];
      #pragma unroll
      for (int rt = 0; rt < 4; ++rt)
        #pragma unroll
        for (int n = 0; n < 4; ++n)
          acc[rt][n] = __builtin_amdgcn_mfma_f32_16x16x32_bf16(av[rt][h], bv[n], acc[rt][n], 0, 0, 0);
    }
  }

  // epilogue: direct scattered bf16 stores + fused BN partials
  // acc element: D[row = rowbase + rt*16 + g*4 + r][col = n*16 + l15]
  float s4[4] = {0.f,0.f,0.f,0.f}, q4[4] = {0.f,0.f,0.f,0.f};
  #pragma unroll
  for (int rt = 0; rt < 4; ++rt){
    #pragma unroll
    for (int r = 0; r < 4; ++r){
      long row = rowbase + rt*16 + g*4 + r;
      if (row < N){
        #pragma unroll
        for (int n = 0; n < 4; ++n){
          float v = acc[rt][n][r];
          s4[n] += v; q4[n] += v*v;
        }
        short* dst = ybf + row*64 + l15;
        dst[0]  = f2bf(acc[rt][0][r]);
        dst[16] = f2bf(acc[rt][1][r]);
        dst[32] = f2bf(acc[rt][2][r]);
        dst[48] = f2bf(acc[rt][3][r]);
      }
    }
  }
  // reduce across g (lane bits 4,5) within wave: xor-shuffle 16, 32
  #pragma unroll
  for (int n = 0; n < 4; ++n){
    s4[n] += __shfl_xor(s4[n], 16, 64);
    s4[n] += __shfl_xor(s4[n], 32, 64);
    q4[n] += __shfl_xor(q4[n], 16, 64);
    q4[n] += __shfl_xor(q4[n], 32, 64);
  }
  if (lane < 16){
    #pragma unroll
    for (int n = 0; n < 4; ++n){
      red[wave][lane][n]   = s4[n];
      red[wave][lane][n+4] = q4[n];
    }
  }
  __syncthreads();
  if (tid < 64){
    int n = tid >> 4, c15 = tid & 15; // channel = n*16 + c15 = tid
    float S = 0.f, Q = 0.f;
    #pragma unroll
    for (int w = 0; w < 4; ++w){
      S += red[w][c15][n];
      Q += red[w][c15][n+4];
    }
    part[(long)blk*64 + tid] = S;
    part[((long)nblk + blk)*64 + tid] = Q;
  }
}

// ---------------- stage1: collapse nblk partials -> 64 partials -------------
__global__ __launch_bounds__(256) void reduce_part(const float* __restrict__ part,
                                                   int nblk, int chunk,
                                                   float* __restrict__ part2){
  int c = threadIdx.x & 63;
  int sl = threadIdx.x >> 6; // 0..3
  int b0 = blockIdx.x * chunk;
  int b1 = min(b0 + chunk, nblk);
  float s = 0.f, q = 0.f;
  for (int b = b0 + sl; b < b1; b += 4){
    s += part[(long)b*64 + c];
    q += part[((long)nblk + b)*64 + c];
  }
  __shared__ float rs[4][64], rq[4][64];
  rs[sl][c] = s; rq[sl][c] = q;
  __syncthreads();
  if (threadIdx.x < 64){
    float S = 0.f, Q = 0.f;
    #pragma unroll
    for (int i = 0; i < 4; ++i){ S += rs[i][threadIdx.x]; Q += rq[i][threadIdx.x]; }
    part2[(long)blockIdx.x*64 + threadIdx.x] = S;
    part2[(long)(64 + blockIdx.x)*64 + threadIdx.x] = Q;
  }
}

// ---------------- stage2: finalize BN affine from 64 partials ---------------
__global__ __launch_bounds__(1024) void finalize_bn(const float* __restrict__ part, int nblk,
                                                    const float* __restrict__ gamma,
                                                    const float* __restrict__ beta, float invN,
                                                    float* __restrict__ scale,
                                                    float* __restrict__ shiftv){
  int t = threadIdx.x;
  int c = t & 63;
  int sl = t >> 6; // 0..15
  float s = 0.f, q = 0.f;
  for (int b = sl; b < nblk; b += 16){
    s += part[(long)b*64 + c];
    q += part[((long)nblk + b)*64 + c];
  }
  __shared__ float rs[16][64], rq[16][64];
  rs[sl][c] = s; rq[sl][c] = q;
  __syncthreads();
  if (t < 64){
    float S = 0.f, Q = 0.f;
    #pragma unroll
    for (int i = 0; i < 16; ++i){ S += rs[i][t]; Q += rq[i][t]; }
    float mean = S * invN;
    float var = Q * invN - mean*mean;
    float sc = gamma[t] * rsqrtf(var + EPS_BN);
    scale[t] = sc;
    shiftv[t] = beta[t] - mean*sc;
  }
}

// ---------------- final: out = relu(y2*scale2+shift2 + feats_bf16) ----------
__global__ __launch_bounds__(256) void final_out(const short* __restrict__ y2,
                                                 const short* __restrict__ f16,
                                                 const float* __restrict__ scale,
                                                 const float* __restrict__ shiftv,
                                                 float* __restrict__ out, long nvec8){
  long t = (long)blockIdx.x * blockDim.x + threadIdx.x;
  long stride = (long)gridDim.x * blockDim.x;  // multiple of 8 -> channel-stable
  int cb = ((int)(t & 7)) * 8;
  float sc[8], sh[8];
  #pragma unroll
  for (int j = 0; j < 8; ++j){ sc[j] = scale[cb+j]; sh[j] = shiftv[cb+j]; }
  for (long v = t; v < nvec8; v += stride){
    s16x8 a = __builtin_nontemporal_load((const s16x8*)y2 + v);
    s16x8 f = __builtin_nontemporal_load((const s16x8*)f16 + v);
    f32x4 r0, r1;
    r0[0] = fmaxf(fmaf(bf2f(a[0]), sc[0], sh[0]) + bf2f(f[0]), 0.f);
    r0[1] = fmaxf(fmaf(bf2f(a[1]), sc[1], sh[1]) + bf2f(f[1]), 0.f);
    r0[2] = fmaxf(fmaf(bf2f(a[2]), sc[2], sh[2]) + bf2f(f[2]), 0.f);
    r0[3] = fmaxf(fmaf(bf2f(a[3]), sc[3], sh[3]) + bf2f(f[3]), 0.f);
    r1[0] = fmaxf(fmaf(bf2f(a[4]), sc[4], sh[4]) + bf2f(f[4]), 0.f);
    r1[1] = fmaxf(fmaf(bf2f(a[5]), sc[5], sh[5]) + bf2f(f[5]), 0.f);
    r1[2] = fmaxf(fmaf(bf2f(a[6]), sc[6], sh[6]) + bf2f(f[6]), 0.f);
    r1[3] = fmaxf(fmaf(bf2f(a[7]), sc[7], sh[7]) + bf2f(f[7]), 0.f);
    f32x4* op = (f32x4*)out + 2*v;
    __builtin_nontemporal_store(r0, op);
    __builtin_nontemporal_store(r1, op + 1);
  }
}

extern "C" void kernel_launch(void* const* d_in, const int* in_sizes, int n_in,
                              void* d_out, int out_size, void* d_ws, size_t ws_size,
                              hipStream_t stream){
  const float* feats = (const float*)d_in[0];
  const float* W1    = (const float*)d_in[1];
  const float* g1    = (const float*)d_in[2];
  const float* b1    = (const float*)d_in[3];
  const float* W2    = (const float*)d_in[4];
  const float* g2    = (const float*)d_in[5];
  const float* b2    = (const float*)d_in[6];
  const int*   nbr1  = (const int*)d_in[7];
  const int*   nbr2  = (const int*)d_in[8];
  float* out = (float*)d_out;

  const int  N  = in_sizes[0] / 64;
  const long NC = (long)N * 64;

  // workspace layout (no aliasing): F16 stays live for the residual read.
  char* ws = (char*)d_ws;
  short* F16 = (short*)ws;                 // NC bf16 (feats, reused as residual)
  short* Y1  = (short*)(ws + NC*2);        // NC bf16 (conv1 raw out)
  short* Y2  = (short*)(ws + NC*4);        // NC bf16 (conv2 raw out)
  char* tail = ws + NC*6;
  short* W1F = (short*)tail;               // 36864 bf16
  short* W2F = W1F + 36864;                // 36864 bf16
  float* scale1 = (float*)(tail + 4*36864);
  float* shift1 = scale1 + 64;
  float* scale2 = shift1 + 64;
  float* shift2 = scale2 + 64;
  float* part   = shift2 + 64;             // 2 * nblk * 64 floats
  const int  nblk  = (N + 255) / 256;
  float* part2  = part + 2L*nblk*64;       // 2 * 64 * 64 floats

  const long nvec8 = NC / 8;
  const int  chunk = (nblk + 63) / 64;
  const int  halfA = (nblk + 1) / 2;
  const int  halfB = nblk - halfA;
  const float invN = 1.0f / (float)N;

  prep<<<288 + 2048, 256, 0, stream>>>(feats, F16, nvec8, W1, W2, W1F, W2F);

  conv_mfma<false><<<halfA, 256, 0, stream>>>(F16, nbr1, W1F, nullptr, nullptr, Y1, part, N, nblk, 0);
  conv_mfma<false><<<halfB, 256, 0, stream>>>(F16, nbr1, W1F, nullptr, nullptr, Y1, part, N, nblk, halfA);
  reduce_part<<<64, 256, 0, stream>>>(part, nblk, chunk, part2);
  finalize_bn<<<1, 1024, 0, stream>>>(part2, 64, g1, b1, invN, scale1, shift1);

  conv_mfma<true><<<halfA, 256, 0, stream>>>(Y1, nbr2, W2F, scale1, shift1, Y2, part, N, nblk, 0);
  conv_mfma<true><<<halfB, 256, 0, stream>>>(Y1, nbr2, W2F, scale1, shift1, Y2, part, N, nblk, halfA);
  reduce_part<<<64, 256, 0, stream>>>(part, nblk, chunk, part2);
  finalize_bn<<<1, 1024, 0, stream>>>(part2, 64, g2, b2, invN, scale2, shift2);

  final_out<<<2048, 256, 0, stream>>>(Y2, F16, scale2, shift2, out, nvec8);
}

// Round 13
// 659.320 us; speedup vs baseline: 1.0317x; 1.0317x over previous
//
#include <hip/hip_runtime.h>
#include <cstdint>

#define EPS_BN 1e-5f

typedef __attribute__((ext_vector_type(8))) short s16x8;
typedef __attribute__((ext_vector_type(4))) float f32x4;
typedef __attribute__((ext_vector_type(4))) unsigned int u32x4;

__device__ __forceinline__ float bf2f(short s){
  unsigned int u = ((unsigned int)(unsigned short)s) << 16;
  return __builtin_bit_cast(float, u);
}
__device__ __forceinline__ unsigned int cvtpk_bf16(float lo, float hi){
  unsigned int r;
  asm("v_cvt_pk_bf16_f32 %0, %1, %2" : "=v"(r) : "v"(lo), "v"(hi));
  return r;
}
__device__ __forceinline__ short f2bf(float f){
  return (short)(unsigned short)(cvtpk_bf16(f, f) & 0xffffu);
}

// ---------------- P0: fused prep: pack W (blocks 0..287) + feats->bf16 ------
// pack layout: frag[t in 0..18)[n in 0..4)[lane in 0..64)[j in 0..8)
//   cin = (t&1)*32 + (lane>>4)*8 + j, cout = n*16 + (lane&15), tap = t>>1
__global__ __launch_bounds__(256) void prep(const float* __restrict__ in,
                                            short* __restrict__ out, long nvec8,
                                            const float* __restrict__ W1,
                                            const float* __restrict__ W2,
                                            short* __restrict__ W1F,
                                            short* __restrict__ W2F){
  if (blockIdx.x < 288){
    int o = blockIdx.x * 256 + threadIdx.x;
    if (o >= 2*36864) return;
    const float* W = (o < 36864) ? W1 : W2;
    short* D = (o < 36864) ? W1F : W2F;
    int oo = o % 36864;
    int j = oo & 7;
    int l = (oo >> 3) & 63;
    int n = (oo >> 9) & 3;
    int t = oo >> 11;
    int tap = t >> 1, h = t & 1, g = l >> 4;
    int cin = h*32 + g*8 + j;
    int cout = n*16 + (l & 15);
    float v = W[((long)tap*64 + cin)*64 + cout];
    D[oo] = f2bf(v);
    return;
  }
  long t = (long)(blockIdx.x - 288) * blockDim.x + threadIdx.x;
  long stride = (long)(gridDim.x - 288) * blockDim.x;
  for (long v = t; v < nvec8; v += stride){
    const f32x4* p = (const f32x4*)in + 2*v;
    f32x4 a = __builtin_nontemporal_load(p);
    f32x4 b = __builtin_nontemporal_load(p + 1);
    u32x4 w;
    w[0] = cvtpk_bf16(a[0], a[1]); w[1] = cvtpk_bf16(a[2], a[3]);
    w[2] = cvtpk_bf16(b[0], b[1]); w[3] = cvtpk_bf16(b[2], b[3]);
    ((u32x4*)out)[v] = w;   // gather table: keep cached
  }
}

// ---------------- conv: Y[N,64] = sum_k gather(src,nbr[:,k]) @ W[k] ----------
// VERBATIM round-9/11 kernel (passed, 253 us): 256-thread blocks, 72 KiB LDS W,
// 2 blocks/CU (low-traffic regime), hoisted nbr indices (plain loads), depth-1
// ping-pong gather pipeline, direct scattered bf16 stores, fused BN partials.
// AFFINE: apply relu(x*scale+shift) to gathered bf16 values (conv2 path).
template<bool AFFINE>
__global__ __launch_bounds__(256, 2) void conv_mfma(const short* __restrict__ src,
                                                    const int* __restrict__ nbr,
                                                    const short* __restrict__ wfrag,
                                                    const float* __restrict__ scale,
                                                    const float* __restrict__ shiftv,
                                                    short* __restrict__ ybf,
                                                    float* __restrict__ part,
                                                    int N, int nblk){
  __shared__ short ldsW[36864]; // 72 KiB: 18 k-steps * 4 col-tiles * 64 lanes * 8 bf16
  __shared__ float red[4][16][8];
  const int tid = threadIdx.x;
  {
    const s16x8* gs = (const s16x8*)wfrag;
    s16x8* ls = (s16x8*)ldsW;
    #pragma unroll
    for (int i = 0; i < 18; ++i) ls[i*256 + tid] = gs[i*256 + tid];
  }
  const int lane = tid & 63;
  const int wave = tid >> 6;
  const int l15 = lane & 15;
  const int g = lane >> 4;
  const long rowbase = (long)blockIdx.x * 256 + wave * 64;

  float sc[2][8], sh[2][8];
  if (AFFINE){
    #pragma unroll
    for (int h = 0; h < 2; ++h)
      #pragma unroll
      for (int j = 0; j < 8; ++j){
        int ch = h*32 + g*8 + j;
        sc[h][j] = scale[ch];
        sh[h][j] = shiftv[ch];
      }
  }

  // hoist ALL neighbor indices (9 taps x 4 row-tiles) before the K loop
  int idx[9][4];
  #pragma unroll
  for (int rt = 0; rt < 4; ++rt){
    long row = rowbase + rt*16 + l15;
    const int* np = nbr + row*9;
    const bool v = (row < N);
    #pragma unroll
    for (int t9 = 0; t9 < 9; ++t9)
      idx[t9][rt] = v ? np[t9] : 0;
  }

  f32x4 acc[4][4];
  #pragma unroll
  for (int rt = 0; rt < 4; ++rt)
    #pragma unroll
    for (int n = 0; n < 4; ++n)
      acc[rt][n] = (f32x4){0.f, 0.f, 0.f, 0.f};

  __syncthreads();

  // depth-1 software pipeline: ping-pong buffers, fully unrolled tap loop
  s16x8 avp[2][4][2];
  #pragma unroll
  for (int rt = 0; rt < 4; ++rt){
    const short* p = src + (long)idx[0][rt]*64 + g*8;
    avp[0][rt][0] = *(const s16x8*)(p);
    avp[0][rt][1] = *(const s16x8*)(p + 32);
  }

  #pragma unroll
  for (int tap = 0; tap < 9; ++tap){
    const int cur = tap & 1, nxt = cur ^ 1;
    if (tap < 8){
      #pragma unroll
      for (int rt = 0; rt < 4; ++rt){
        const short* p = src + (long)idx[tap+1][rt]*64 + g*8;
        avp[nxt][rt][0] = *(const s16x8*)(p);
        avp[nxt][rt][1] = *(const s16x8*)(p + 32);
      }
    }
    s16x8 av[4][2];
    #pragma unroll
    for (int rt = 0; rt < 4; ++rt){
      av[rt][0] = avp[cur][rt][0];
      av[rt][1] = avp[cur][rt][1];
    }
    if (AFFINE){
      #pragma unroll
      for (int rt = 0; rt < 4; ++rt)
        #pragma unroll
        for (int h = 0; h < 2; ++h){
          u32x4 w = __builtin_bit_cast(u32x4, av[rt][h]);
          #pragma unroll
          for (int jw = 0; jw < 4; ++jw){
            float f0 = __builtin_bit_cast(float, w[jw] << 16);
            float f1 = __builtin_bit_cast(float, w[jw] & 0xffff0000u);
            f0 = fmaxf(fmaf(f0, sc[h][2*jw],   sh[h][2*jw]),   0.f);
            f1 = fmaxf(fmaf(f1, sc[h][2*jw+1], sh[h][2*jw+1]), 0.f);
            w[jw] = cvtpk_bf16(f0, f1);
          }
          av[rt][h] = __builtin_bit_cast(s16x8, w);
        }
    }
    #pragma unroll
    for (int h = 0; h < 2; ++h){
      const int t = tap*2 + h;
      s16x8 bv[4];
      #pragma unroll
      for (int n = 0; n < 4; ++n)
        bv[n] = *(const s16x8*)&ldsW[((t*4 + n)*64 + lane)*8];
      #pragma unroll
      for (int rt = 0; rt < 4; ++rt)
        #pragma unroll
        for (int n = 0; n < 4; ++n)
          acc[rt][n] = __builtin_amdgcn_mfma_f32_16x16x32_bf16(av[rt][h], bv[n], acc[rt][n], 0, 0, 0);
    }
  }

  // epilogue: direct scattered bf16 stores + fused BN partials
  // acc element: D[row = rowbase + rt*16 + g*4 + r][col = n*16 + l15]
  float s4[4] = {0.f,0.f,0.f,0.f}, q4[4] = {0.f,0.f,0.f,0.f};
  #pragma unroll
  for (int rt = 0; rt < 4; ++rt){
    #pragma unroll
    for (int r = 0; r < 4; ++r){
      long row = rowbase + rt*16 + g*4 + r;
      if (row < N){
        #pragma unroll
        for (int n = 0; n < 4; ++n){
          float v = acc[rt][n][r];
          s4[n] += v; q4[n] += v*v;
        }
        short* dst = ybf + row*64 + l15;
        dst[0]  = f2bf(acc[rt][0][r]);
        dst[16] = f2bf(acc[rt][1][r]);
        dst[32] = f2bf(acc[rt][2][r]);
        dst[48] = f2bf(acc[rt][3][r]);
      }
    }
  }
  // reduce across g (lane bits 4,5) within wave: xor-shuffle 16, 32
  #pragma unroll
  for (int n = 0; n < 4; ++n){
    s4[n] += __shfl_xor(s4[n], 16, 64);
    s4[n] += __shfl_xor(s4[n], 32, 64);
    q4[n] += __shfl_xor(q4[n], 16, 64);
    q4[n] += __shfl_xor(q4[n], 32, 64);
  }
  if (lane < 16){
    #pragma unroll
    for (int n = 0; n < 4; ++n){
      red[wave][lane][n]   = s4[n];
      red[wave][lane][n+4] = q4[n];
    }
  }
  __syncthreads();
  if (tid < 64){
    int n = tid >> 4, c15 = tid & 15; // channel = n*16 + c15 = tid
    float S = 0.f, Q = 0.f;
    #pragma unroll
    for (int w = 0; w < 4; ++w){
      S += red[w][c15][n];
      Q += red[w][c15][n+4];
    }
    part[(long)blockIdx.x*64 + tid] = S;
    part[((long)nblk + blockIdx.x)*64 + tid] = Q;
  }
}

// ---------------- stage1: collapse nblk partials -> 64 partials -------------
__global__ __launch_bounds__(256) void reduce_part(const float* __restrict__ part,
                                                   int nblk, int chunk,
                                                   float* __restrict__ part2){
  int c = threadIdx.x & 63;
  int sl = threadIdx.x >> 6; // 0..3
  int b0 = blockIdx.x * chunk;
  int b1 = min(b0 + chunk, nblk);
  float s = 0.f, q = 0.f;
  for (int b = b0 + sl; b < b1; b += 4){
    s += part[(long)b*64 + c];
    q += part[((long)nblk + b)*64 + c];
  }
  __shared__ float rs[4][64], rq[4][64];
  rs[sl][c] = s; rq[sl][c] = q;
  __syncthreads();
  if (threadIdx.x < 64){
    float S = 0.f, Q = 0.f;
    #pragma unroll
    for (int i = 0; i < 4; ++i){ S += rs[i][threadIdx.x]; Q += rq[i][threadIdx.x]; }
    part2[(long)blockIdx.x*64 + threadIdx.x] = S;
    part2[(long)(64 + blockIdx.x)*64 + threadIdx.x] = Q;
  }
}

// ---------------- stage2: finalize BN affine from 64 partials ---------------
__global__ __launch_bounds__(1024) void finalize_bn(const float* __restrict__ part, int nblk,
                                                    const float* __restrict__ gamma,
                                                    const float* __restrict__ beta, float invN,
                                                    float* __restrict__ scale,
                                                    float* __restrict__ shiftv){
  int t = threadIdx.x;
  int c = t & 63;
  int sl = t >> 6; // 0..15
  float s = 0.f, q = 0.f;
  for (int b = sl; b < nblk; b += 16){
    s += part[(long)b*64 + c];
    q += part[((long)nblk + b)*64 + c];
  }
  __shared__ float rs[16][64], rq[16][64];
  rs[sl][c] = s; rq[sl][c] = q;
  __syncthreads();
  if (t < 64){
    float S = 0.f, Q = 0.f;
    #pragma unroll
    for (int i = 0; i < 16; ++i){ S += rs[i][t]; Q += rq[i][t]; }
    float mean = S * invN;
    float var = Q * invN - mean*mean;
    float sc = gamma[t] * rsqrtf(var + EPS_BN);
    scale[t] = sc;
    shiftv[t] = beta[t] - mean*sc;
  }
}

// ---------------- final: out = relu(y2*scale2+shift2 + feats_bf16) ----------
__global__ __launch_bounds__(256) void final_out(const short* __restrict__ y2,
                                                 const short* __restrict__ f16,
                                                 const float* __restrict__ scale,
                                                 const float* __restrict__ shiftv,
                                                 float* __restrict__ out, long nvec8){
  long t = (long)blockIdx.x * blockDim.x + threadIdx.x;
  long stride = (long)gridDim.x * blockDim.x;  // multiple of 8 -> channel-stable
  int cb = ((int)(t & 7)) * 8;
  float sc[8], sh[8];
  #pragma unroll
  for (int j = 0; j < 8; ++j){ sc[j] = scale[cb+j]; sh[j] = shiftv[cb+j]; }
  for (long v = t; v < nvec8; v += stride){
    s16x8 a = __builtin_nontemporal_load((const s16x8*)y2 + v);
    s16x8 f = __builtin_nontemporal_load((const s16x8*)f16 + v);
    f32x4 r0, r1;
    r0[0] = fmaxf(fmaf(bf2f(a[0]), sc[0], sh[0]) + bf2f(f[0]), 0.f);
    r0[1] = fmaxf(fmaf(bf2f(a[1]), sc[1], sh[1]) + bf2f(f[1]), 0.f);
    r0[2] = fmaxf(fmaf(bf2f(a[2]), sc[2], sh[2]) + bf2f(f[2]), 0.f);
    r0[3] = fmaxf(fmaf(bf2f(a[3]), sc[3], sh[3]) + bf2f(f[3]), 0.f);
    r1[0] = fmaxf(fmaf(bf2f(a[4]), sc[4], sh[4]) + bf2f(f[4]), 0.f);
    r1[1] = fmaxf(fmaf(bf2f(a[5]), sc[5], sh[5]) + bf2f(f[5]), 0.f);
    r1[2] = fmaxf(fmaf(bf2f(a[6]), sc[6], sh[6]) + bf2f(f[6]), 0.f);
    r1[3] = fmaxf(fmaf(bf2f(a[7]), sc[7], sh[7]) + bf2f(f[7]), 0.f);
    f32x4* op = (f32x4*)out + 2*v;
    __builtin_nontemporal_store(r0, op);
    __builtin_nontemporal_store(r1, op + 1);
  }
}

extern "C" void kernel_launch(void* const* d_in, const int* in_sizes, int n_in,
                              void* d_out, int out_size, void* d_ws, size_t ws_size,
                              hipStream_t stream){
  const float* feats = (const float*)d_in[0];
  const float* W1    = (const float*)d_in[1];
  const float* g1    = (const float*)d_in[2];
  const float* b1    = (const float*)d_in[3];
  const float* W2    = (const float*)d_in[4];
  const float* g2    = (const float*)d_in[5];
  const float* b2    = (const float*)d_in[6];
  const int*   nbr1  = (const int*)d_in[7];
  const int*   nbr2  = (const int*)d_in[8];
  float* out = (float*)d_out;

  const int  N  = in_sizes[0] / 64;
  const long NC = (long)N * 64;

  // workspace layout (no aliasing): F16 stays live for the residual read.
  char* ws = (char*)d_ws;
  short* F16 = (short*)ws;                 // NC bf16 (feats, reused as residual)
  short* Y1  = (short*)(ws + NC*2);        // NC bf16 (conv1 raw out)
  short* Y2  = (short*)(ws + NC*4);        // NC bf16 (conv2 raw out)
  char* tail = ws + NC*6;
  short* W1F = (short*)tail;               // 36864 bf16
  short* W2F = W1F + 36864;                // 36864 bf16
  float* scale1 = (float*)(tail + 4*36864);
  float* shift1 = scale1 + 64;
  float* scale2 = shift1 + 64;
  float* shift2 = scale2 + 64;
  float* part   = shift2 + 64;             // 2 * nblk * 64 floats
  const int  nblk  = (N + 255) / 256;
  float* part2  = part + 2L*nblk*64;       // 2 * 64 * 64 floats

  const long nvec8 = NC / 8;
  const int  chunk = (nblk + 63) / 64;
  const float invN = 1.0f / (float)N;

  prep<<<288 + 2048, 256, 0, stream>>>(feats, F16, nvec8, W1, W2, W1F, W2F);

  conv_mfma<false><<<nblk, 256, 0, stream>>>(F16, nbr1, W1F, nullptr, nullptr, Y1, part, N, nblk);
  reduce_part<<<64, 256, 0, stream>>>(part, nblk, chunk, part2);
  finalize_bn<<<1, 1024, 0, stream>>>(part2, 64, g1, b1, invN, scale1, shift1);

  conv_mfma<true><<<nblk, 256, 0, stream>>>(Y1, nbr2, W2F, scale1, shift1, Y2, part, N, nblk);
  reduce_part<<<64, 256, 0, stream>>>(part, nblk, chunk, part2);
  finalize_bn<<<1, 1024, 0, stream>>>(part2, 64, g2, b2, invN, scale2, shift2);

  final_out<<<2048, 256, 0, stream>>>(Y2, F16, scale2, shift2, out, nvec8);
}